// Round 8
// baseline (179.037 us; speedup 1.0000x reference)
//
#include <hip/hip_runtime.h>
#include <hip/hip_bf16.h>

// Problem constants (fixed by setup_inputs)
#define Bq 2
#define Lq 2048
#define BLq (Bq*Lq)          // 4096
#define KNB 48
#define NA 14
#define NTOK 21
#define NRBF 16
#define POSD 16
#define EOUT 128
#define CSTRIDE 168          // chunked A row stride (bf16 elems), 336B
#define E_ELEMS (BLq*KNB*EOUT)   // 25165824

typedef __attribute__((ext_vector_type(8))) short short8;
typedef __attribute__((ext_vector_type(4))) float f32x4;

__device__ __forceinline__ unsigned short bf16_rn(float x) {
    unsigned int u = __float_as_uint(x);
    unsigned int r = (u + 0x7fffu + ((u >> 16) & 1u)) >> 16;
    return (unsigned short)r;
}

__device__ __forceinline__ unsigned int pkbf2(float a, float b) {
    __hip_bfloat162 t = __float22bfloat162_rn(make_float2(a, b));
    union { __hip_bfloat162 h; unsigned int u; } cv; cv.h = t;
    return cv.u;
}

// ---------------- Kernel P: fused [xall (16 blocks)] + [W_e pack (208 blocks)] ----
__global__ void prep_kernel(const float* __restrict__ X, const int* __restrict__ S,
                            const int* __restrict__ table, const float* __restrict__ mask,
                            const float* __restrict__ We,
                            float* __restrict__ Xall, float4* __restrict__ CA4,
                            short* __restrict__ Wp) {
    int bid = blockIdx.x;
    if (bid < 16) {
        int t = bid * 256 + threadIdx.x;
        if (t >= BLq) return;
        int s = S[t];
        float bb[4][3];
#pragma unroll
        for (int a = 0; a < 4; ++a) {
            int ia = table[s * 4 + a];
#pragma unroll
            for (int d = 0; d < 3; ++d) bb[a][d] = X[(t * NA + ia) * 3 + d];
        }
        float b1[3], b2[3], nr[3];
#pragma unroll
        for (int d = 0; d < 3; ++d) { b1[d] = bb[0][d] - bb[1][d]; b2[d] = bb[2][d] - bb[1][d]; }
        nr[0] = b1[1] * b2[2] - b1[2] * b2[1];
        nr[1] = b1[2] * b2[0] - b1[0] * b2[2];
        nr[2] = b1[0] * b2[1] - b1[1] * b2[0];
#pragma unroll
        for (int a = 0; a < 4; ++a)
#pragma unroll
            for (int d = 0; d < 3; ++d) Xall[t * 15 + a * 3 + d] = bb[a][d];
#pragma unroll
        for (int d = 0; d < 3; ++d) {
            float xv = 0.58273431f * nr[d] + (-0.56802827f) * b1[d] + (-0.54067466f) * b2[d] + bb[1][d];
            Xall[t * 15 + 12 + d] = xv;
        }
        CA4[t] = make_float4(bb[1][0], bb[1][1], bb[1][2], mask[t]);
    } else {
        // pack W_e (416x128) into MFMA B-fragment order, bf16
        int t = (bid - 16) * 256 + threadIdx.x;
        if (t >= 13 * 8 * 64 * 8) return;
        int j = t & 7;
        int lane = (t >> 3) & 63;
        int nt = (t >> 9) & 7;
        int kt = t >> 12;
        int k = kt * 32 + (lane >> 4) * 8 + j;
        int n = nt * 16 + (lane & 15);
        Wp[t] = (short)bf16_rn(We[k * 128 + n]);
    }
}

// RBF row of 16 values via 2-anchor ratio recurrence: 6 exp2 instead of 16.
__device__ __forceinline__ void rbf16(float D, unsigned short* dst) {
    const float s1   = 0.96089793f;    // 0.8*sqrt(log2 e)
    const float dlt2 = 1.64146638f;    // dlt^2
    const float tdl  = 2.56239448f;    // 2*dlt
    const float Cg   = 0.10273972f;    // exp2(-2*dlt^2)
    float u0 = __builtin_fmaf(D, s1, -1.92179585f);   // c00 = 2*s1
    uint4 qa, qb;
    {
        float ua = u0 - 5.12478895f;                  // anchor i=4
        float va = __builtin_amdgcn_exp2f(-(ua * ua));
        float eu = fminf(__builtin_fmaf(tdl, ua, -dlt2), 120.0f);   // clamp: avoid 0*inf=NaN
        float ed = fminf(__builtin_fmaf(-tdl, ua, -dlt2), 120.0f);
        float gu = __builtin_amdgcn_exp2f(eu);
        float gd = __builtin_amdgcn_exp2f(ed);
        float v4 = va;
        float v5 = v4 * gu; float g2 = gu * Cg;
        float v6 = v5 * g2;
        float v7 = v6 * (g2 * Cg);
        float v3 = v4 * gd; float h2 = gd * Cg;
        float v2 = v3 * h2; float h3 = h2 * Cg;
        float v1 = v2 * h3;
        float v0 = v1 * (h3 * Cg);
        qa.x = pkbf2(v0, v1); qa.y = pkbf2(v2, v3);
        qa.z = pkbf2(v4, v5); qa.w = pkbf2(v6, v7);
    }
    {
        float ub = u0 - 15.37436684f;                 // anchor i=12
        float vb = __builtin_amdgcn_exp2f(-(ub * ub));
        float eu = fminf(__builtin_fmaf(tdl, ub, -dlt2), 120.0f);
        float ed = fminf(__builtin_fmaf(-tdl, ub, -dlt2), 120.0f);
        float gu = __builtin_amdgcn_exp2f(eu);
        float gd = __builtin_amdgcn_exp2f(ed);
        float v12 = vb;
        float v13 = v12 * gu; float g2 = gu * Cg;
        float v14 = v13 * g2;
        float v15 = v14 * (g2 * Cg);
        float v11 = v12 * gd; float h2 = gd * Cg;
        float v10 = v11 * h2; float h3 = h2 * Cg;
        float v9  = v10 * h3;
        float v8  = v9 * (h3 * Cg);
        qb.x = pkbf2(v8, v9);   qb.y = pkbf2(v10, v11);
        qb.z = pkbf2(v12, v13); qb.w = pkbf2(v14, v15);
    }
    *(uint4*)dst = qa;
    *(uint4*)(dst + 8) = qb;
}

// ---------------- Fused kernel: exact 48-NN topk -> features -> MFMA GEMM^T -> LN ----
// LDS union (19456 B -> 19968 w/ granule -> 8 blocks/CU):
//  topk phase:  [0..16384) hist 4096 bins u32 | [16384..17408) buf[128] u64
//  edge phase:  [0..16128) Asm bf16[48*168] | [16128..16192) Xq | [16192..19072) Xn
//               [19072..19264) eidxl
//  LN phase:    partials overlays Xn [16192..17728) ; stats float2[48] overlays eidxl
__global__ __launch_bounds__(256, 8) void edge_kernel(
    const float4* __restrict__ CA4, const float* __restrict__ Xall,
    const int* __restrict__ ridx, const float* __restrict__ Wpos,
    const float* __restrict__ bpos, const short* __restrict__ Wp,
    const float* __restrict__ lng, const float* __restrict__ lnb,
    float* __restrict__ out, float* __restrict__ out_idx) {
    __shared__ __align__(16) char smem[19456];
    unsigned int* histR = (unsigned int*)smem;                       // 4096 u32
    unsigned int* hist8 = (unsigned int*)smem;                       // 256 u32 (fallback)
    unsigned long long* buf = (unsigned long long*)(smem + 16384);   // 128 u64
    unsigned short* Asm = (unsigned short*)smem;
    float* Xq = (float*)(smem + 16128);
    float* Xn = (float*)(smem + 16192);
    int* eidxl = (int*)(smem + 19072);
    float2* stats = (float2*)(smem + 19072);                         // overlays eidxl (dead by LN)
    float* partials = (float*)(smem + 16192);                        // overlays Xn (dead by LN)
    __shared__ unsigned int nacc, wtot[4];
    __shared__ int sh_bin, sh_excl, sh_cnt;

    int bl = blockIdx.x;
    int base = (bl >> 11) << 11;
    int tid = threadIdx.x;
    int w = tid >> 6, lane = tid & 63;

    // ======================= phase T: exact top-48 =======================
    float4 q = CA4[bl];
    unsigned long long key[8];
#pragma unroll
    for (int i = 0; i < 8; ++i) {
        int j = tid + (i << 8);
        float4 c = CA4[base + j];
        float dx = __fsub_rn(q.x, c.x);
        float dy = __fsub_rn(q.y, c.y);
        float dz = __fsub_rn(q.z, c.z);
        // match numpy: ((dx*dx + dy*dy) + dz*dz) + 1e-6, no FMA contraction
        float s = __fadd_rn(__fadd_rn(__fmul_rn(dx, dx), __fmul_rn(dy, dy)), __fmul_rn(dz, dz));
        float D = __fsqrt_rn(__fadd_rn(s, 1e-6f));
        float m2 = __fmul_rn(q.w, c.w);
        float Dadj = __fadd_rn(__fmul_rn(D, m2), __fmul_rn(__fsub_rn(1.0f, m2), 1000000.0f));
        key[i] = (((unsigned long long)__float_as_uint(Dadj)) << 16) | (unsigned int)j;
    }

    // pass 1: 12-bit bins from key bits 46:35 (sign bit 47 is always 0) =
    // exp(8) + 4 mantissa bits -> 16 sub-bins/octave, fallback essentially never
    {
        uint4 z = make_uint4(0u, 0u, 0u, 0u);
#pragma unroll
        for (int i = 0; i < 4; ++i) ((uint4*)histR)[tid + (i << 8)] = z;
    }
    __syncthreads();
#pragma unroll
    for (int i = 0; i < 8; ++i)
        atomicAdd(&histR[(unsigned int)((key[i] >> 35) & 4095ull)], 1u);
    __syncthreads();

    // segmented scan over 4096 bins: 16 contiguous bins per thread
    unsigned int loc[16], lsum = 0;
#pragma unroll
    for (int j = 0; j < 4; ++j) {
        uint4 r4 = ((const uint4*)histR)[tid * 4 + j];
        loc[4 * j + 0] = r4.x; loc[4 * j + 1] = r4.y;
        loc[4 * j + 2] = r4.z; loc[4 * j + 3] = r4.w;
        lsum += (r4.x + r4.y) + (r4.z + r4.w);
    }
    unsigned int incl = lsum;
#pragma unroll
    for (int o = 1; o < 64; o <<= 1) {
        unsigned int v = __shfl_up(incl, o);
        if (lane >= o) incl += v;
    }
    if (lane == 63) wtot[w] = incl;
    __syncthreads();
    unsigned int cum = incl - lsum;
#pragma unroll
    for (int u = 0; u < 4; ++u) cum += (u < w) ? wtot[u] : 0u;
#pragma unroll
    for (int j = 0; j < 16; ++j) {
        if ((int)cum < 48 && 48 <= (int)(cum + loc[j])) {   // exactly one (tid,j)
            sh_bin = tid * 16 + j;
            sh_excl = (int)cum;
            sh_cnt = (int)loc[j];
        }
        cum += loc[j];
    }
    if (tid == 0) nacc = 0;   // covered by the barrier below
    __syncthreads();

    unsigned long long prefix = (unsigned long long)(unsigned int)sh_bin;
    int need = 48 - sh_excl;
    int cnt = sh_cnt;
    int shift = 35;

    // rare fallback: 8-bit refinement rounds
    while (cnt > 80 && shift > 0) {
        shift = (shift >= 8) ? (shift - 8) : 0;
        hist8[tid] = 0;
        __syncthreads();
#pragma unroll
        for (int i = 0; i < 8; ++i)
            if ((key[i] >> (shift + 8)) == prefix)
                atomicAdd(&hist8[(unsigned int)((key[i] >> shift) & 255ull)], 1u);
        __syncthreads();
        if (tid < 64) {
            unsigned int h0 = hist8[4 * tid + 0], h1 = hist8[4 * tid + 1];
            unsigned int h2 = hist8[4 * tid + 2], h3 = hist8[4 * tid + 3];
            unsigned int s4 = h0 + h1 + h2 + h3;
            unsigned int incl2 = s4;
#pragma unroll
            for (int o = 1; o < 64; o <<= 1) {
                unsigned int v = __shfl_up(incl2, o);
                if (tid >= o) incl2 += v;
            }
            unsigned int excl2 = incl2 - s4;
            if ((int)excl2 < need && need <= (int)incl2) {   // exactly one lane
                unsigned int cb = excl2;
                unsigned int hh[4] = {h0, h1, h2, h3};
                int bsel = 3;
#pragma unroll
                for (int bb2 = 0; bb2 < 4; ++bb2) {
                    if ((int)(cb + hh[bb2]) >= need) { bsel = bb2; break; }
                    cb += hh[bb2];
                }
                sh_bin = 4 * tid + bsel;
                sh_excl = (int)cb;
                sh_cnt = (int)hh[bsel];
            }
        }
        __syncthreads();
        prefix = (prefix << 8) | (unsigned long long)(unsigned int)sh_bin;
        need -= sh_excl;
        cnt = sh_cnt;
    }

    // collect: wave-aggregated push of definite + candidate keys (<=128)
#pragma unroll
    for (int i = 0; i < 8; ++i) {
        bool p = (key[i] >> shift) <= prefix;
        unsigned long long m = __ballot(p);
        if (m != 0ull) {
            int leader = __ffsll((long long)m) - 1;
            unsigned int bp2 = 0;
            if (lane == leader) bp2 = atomicAdd(&nacc, (unsigned int)__popcll(m));
            bp2 = (unsigned int)__shfl((int)bp2, leader);
            if (p) {
                unsigned int pos = bp2 + (unsigned int)__popcll(m & ((1ull << lane) - 1ull));
                if (pos < 128) buf[pos] = key[i];
            }
        }
    }
    __syncthreads();
    int mcnt = (int)nacc;
    if (mcnt > 128) mcnt = 128;

    // rank: 2 threads per entry, each counts half of [0,mcnt), combine via shfl
    if (tid < 2 * mcnt) {
        int e = tid >> 1, h = tid & 1;
        unsigned long long k = buf[e];
        int lo = h ? (mcnt >> 1) : 0;
        int hi = h ? mcnt : (mcnt >> 1);
        int rank = 0;
        for (int u = lo; u < hi; ++u) rank += (buf[u] < k) ? 1 : 0;
        rank += __shfl_xor(rank, 1);     // partner tid^1 = other half of same entry
        if (h == 0 && rank < KNB) {
            int j = (int)(k & 0xffffull);
            eidxl[rank] = j;
            __builtin_nontemporal_store((float)j, &out_idx[bl * KNB + rank]);
        }
    }
    __syncthreads();

    // ======================= phase E: edge features =======================
    int myoff = 0;                      // rel-pos offset lives in a register:
    if (tid < KNB) {                    // producer thread == consumer thread
        int j = eidxl[tid];
        myoff = min(max(ridx[bl] - ridx[base + j] + 32, 0), 64);
    }
    if (tid < 15) Xq[tid] = Xall[bl * 15 + tid];
    for (int f = tid; f < KNB * 15; f += 256) {
        int k = f / 15, d = f - k * 15;
        int j = eidxl[k];
        Xn[f] = Xall[(base + j) * 15 + d];
    }
    __syncthreads();

    int quad = lane >> 4, lr = lane & 15;
    // acc[et][wt]: E^T tile -- edge tile et (N dim), EOUT tile 2w+wt (M dim).
    // lane holds: edge = et*16 + (lane&15), EOUT cols = (2w+wt)*16 + quad*4 + r
    f32x4 acc[3][2];
#pragma unroll
    for (int et = 0; et < 3; ++et)
#pragma unroll
        for (int wt = 0; wt < 2; ++wt) acc[et][wt] = (f32x4){0.f, 0.f, 0.f, 0.f};

    auto gemm_chunk = [&](int ktBase, int ktCnt) {
#pragma unroll
        for (int ktl = 0; ktl < ktCnt; ++ktl) {
            int kt = ktBase + ktl;
            short8 bf0 = *(const short8*)(Wp + (((kt * 8 + 2 * w + 0) * 64 + lane) << 3));
            short8 bf1 = *(const short8*)(Wp + (((kt * 8 + 2 * w + 1) * 64 + lane) << 3));
#pragma unroll
            for (int et = 0; et < 3; ++et) {
                short8 af = *(const short8*)(&Asm[(et * 16 + lr) * CSTRIDE + ktl * 32 + quad * 8]);
                // swapped operands: D = W^T x A^T = E^T  (A/B frag layouts are symmetric)
                acc[et][0] = __builtin_amdgcn_mfma_f32_16x16x32_bf16(bf0, af, acc[et][0], 0, 0, 0);
                acc[et][1] = __builtin_amdgcn_mfma_f32_16x16x32_bf16(bf1, af, acc[et][1], 0, 0, 0);
            }
        }
    };

    // RBF fill with inline distance (each (edge,pair) D used exactly once).
    // fast v_sqrt here: result feeds exp2 -> bf16; 1-ulp D error << bf16 step.
    auto fill_rbf = [&](int prBase, int prCount, int colBase) {
        for (int it = tid; it < prCount * KNB; it += 256) {
            int prl = it / KNB, k = it - prl * KNB;
            int pr = prBase + prl;
            int a = pr / 5, c = pr - a * 5;
            float dx = Xq[a * 3 + 0] - Xn[k * 15 + c * 3 + 0];
            float dy = Xq[a * 3 + 1] - Xn[k * 15 + c * 3 + 1];
            float dz = Xq[a * 3 + 2] - Xn[k * 15 + c * 3 + 2];
            float D = __builtin_amdgcn_sqrtf(dx * dx + dy * dy + dz * dz + 1e-6f);
            rbf16(D, Asm + k * CSTRIDE + colBase + prl * 16);
        }
    };

    // ---- chunk 0: kt 0..4, cols 0..159 (16 pos cols + atom-pairs 0..8) ----
    if (tid < KNB) {
        const float4* wr = (const float4*)(Wpos + myoff * 16);
        const float4* bp = (const float4*)bpos;
        float4 a0 = wr[0], a1 = wr[1], a2 = wr[2], a3 = wr[3];
        float4 b0 = bp[0], b1 = bp[1], b2 = bp[2], b3 = bp[3];
        uint4 o1, o2;
        o1.x = pkbf2(a0.x + b0.x, a0.y + b0.y); o1.y = pkbf2(a0.z + b0.z, a0.w + b0.w);
        o1.z = pkbf2(a1.x + b1.x, a1.y + b1.y); o1.w = pkbf2(a1.z + b1.z, a1.w + b1.w);
        o2.x = pkbf2(a2.x + b2.x, a2.y + b2.y); o2.y = pkbf2(a2.z + b2.z, a2.w + b2.w);
        o2.z = pkbf2(a3.x + b3.x, a3.y + b3.y); o2.w = pkbf2(a3.z + b3.z, a3.w + b3.w);
        unsigned short* dst = Asm + tid * CSTRIDE;
        *(uint4*)dst = o1;
        *(uint4*)(dst + 8) = o2;
    }
    fill_rbf(0, 9, 16);
    __syncthreads();
    gemm_chunk(0, 5);
    __syncthreads();

    // ---- chunk 1: kt 5..8, cols 160..287 (atom-pairs 9..16) ----
    fill_rbf(9, 8, 0);
    __syncthreads();
    gemm_chunk(5, 4);
    __syncthreads();

    // ---- chunk 2: kt 9..12, cols 288..415 (atom-pairs 17..24) ----
    fill_rbf(17, 8, 0);
    __syncthreads();
    gemm_chunk(9, 4);
    // (no barrier needed: all Xn reads completed before the pre-gemm barrier;
    //  partials [16192,17728) is disjoint from Asm [0,16128) that gemm reads)

    // ======================= phase L: LayerNorm (E^T layout) =======================
    // lane owns 8 cols of edge (et*16+lr) per et: local sum + 2-step quad reduce
#pragma unroll
    for (int et = 0; et < 3; ++et) {
        float s = 0.f, qs = 0.f;
#pragma unroll
        for (int wt = 0; wt < 2; ++wt)
#pragma unroll
            for (int r = 0; r < 4; ++r) {
                float v = acc[et][wt][r];
                s += v;
                qs = __builtin_fmaf(v, v, qs);
            }
        s += __shfl_xor(s, 16); qs += __shfl_xor(qs, 16);
        s += __shfl_xor(s, 32); qs += __shfl_xor(qs, 32);
        if (quad == 0)
            *(float2*)(partials + (et * 16 + lr) * 8 + w * 2) = make_float2(s, qs);
    }
    __syncthreads();

    if (tid < KNB) {
        float4 p0 = *(const float4*)(partials + tid * 8);
        float4 p1 = *(const float4*)(partials + tid * 8 + 4);
        float s = (p0.x + p0.z) + (p1.x + p1.z);
        float qs = (p0.y + p0.w) + (p1.y + p1.w);
        float mean = s * 0.0078125f;
        float var = __builtin_fmaf(-mean, mean, qs * 0.0078125f);
        stats[tid] = make_float2(mean, rsqrtf(var + 1e-5f));
    }
    __syncthreads();

    // normalize + float4 nontemporal stores (r6-best: keeps L2 for the read-set)
    f32x4 gv[2], bv[2];
#pragma unroll
    for (int wt = 0; wt < 2; ++wt) {
        int col = (2 * w + wt) * 16 + quad * 4;
        gv[wt] = *(const f32x4*)(lng + col);
        bv[wt] = *(const f32x4*)(lnb + col);
    }
#pragma unroll
    for (int et = 0; et < 3; ++et) {
        float2 st = stats[et * 16 + lr];
        float mean = st.x, inv = st.y;
        int erow = bl * KNB + et * 16 + lr;
#pragma unroll
        for (int wt = 0; wt < 2; ++wt) {
            int col = (2 * w + wt) * 16 + quad * 4;
            f32x4 o;
#pragma unroll
            for (int r = 0; r < 4; ++r)
                o[r] = __builtin_fmaf(acc[et][wt][r] - mean, inv * gv[wt][r], bv[wt][r]);
            __builtin_nontemporal_store(o, (f32x4*)(out + erow * EOUT + col));
        }
    }
}

extern "C" void kernel_launch(void* const* d_in, const int* in_sizes, int n_in,
                              void* d_out, int out_size, void* d_ws, size_t ws_size,
                              hipStream_t stream) {
    const float* X    = (const float*)d_in[0];
    // d_in[1] = X_m (unused by reference)
    const int*   S    = (const int*)d_in[2];
    const int*   ridx = (const int*)d_in[3];
    const float* mask = (const float*)d_in[4];
    const int*   tab  = (const int*)d_in[5];
    const float* Wpos = (const float*)d_in[6];
    const float* bpos = (const float*)d_in[7];
    const float* We   = (const float*)d_in[8];
    const float* lng  = (const float*)d_in[9];
    const float* lnb  = (const float*)d_in[10];
    float* out = (float*)d_out;

    char* ws = (char*)d_ws;
    float*  Xall = (float*)ws;                         // 4096*15*4   = 245760 B
    short*  Wp   = (short*)(ws + 245760);              // 53248*2     = 106496 B
    float4* CA4  = (float4*)(ws + 245760 + 106496);    // 4096*16     = 65536 B

    prep_kernel<<<224, 256, 0, stream>>>(X, S, tab, mask, We, Xall, CA4, Wp);
    edge_kernel<<<BLq, 256, 0, stream>>>(CA4, Xall, ridx, Wpos, bpos, Wp, lng, lnb,
                                         out, out + E_ELEMS);
}

// Round 9
// 167.355 us; speedup vs baseline: 1.0698x; 1.0698x over previous
//
#include <hip/hip_runtime.h>
#include <hip/hip_bf16.h>

// Problem constants (fixed by setup_inputs)
#define Bq 2
#define Lq 2048
#define BLq (Bq*Lq)          // 4096
#define KNB 48
#define NA 14
#define NTOK 21
#define NRBF 16
#define POSD 16
#define EOUT 128
#define CSTRIDE 168          // chunked A row stride (bf16 elems), 336B
#define E_ELEMS (BLq*KNB*EOUT)   // 25165824

typedef __attribute__((ext_vector_type(8))) short short8;
typedef __attribute__((ext_vector_type(4))) float f32x4;

__device__ __forceinline__ unsigned short bf16_rn(float x) {
    unsigned int u = __float_as_uint(x);
    unsigned int r = (u + 0x7fffu + ((u >> 16) & 1u)) >> 16;
    return (unsigned short)r;
}

__device__ __forceinline__ unsigned int pkbf2(float a, float b) {
    __hip_bfloat162 t = __float22bfloat162_rn(make_float2(a, b));
    union { __hip_bfloat162 h; unsigned int u; } cv; cv.h = t;
    return cv.u;
}

// ---------------- Kernel P: fused [xall (16 blocks)] + [W_e pack (208 blocks)] ----
__global__ void prep_kernel(const float* __restrict__ X, const int* __restrict__ S,
                            const int* __restrict__ table, const float* __restrict__ mask,
                            const float* __restrict__ We,
                            float* __restrict__ Xall, float4* __restrict__ CA4,
                            short* __restrict__ Wp) {
    int bid = blockIdx.x;
    if (bid < 16) {
        int t = bid * 256 + threadIdx.x;
        if (t >= BLq) return;
        int s = S[t];
        float bb[4][3];
#pragma unroll
        for (int a = 0; a < 4; ++a) {
            int ia = table[s * 4 + a];
#pragma unroll
            for (int d = 0; d < 3; ++d) bb[a][d] = X[(t * NA + ia) * 3 + d];
        }
        float b1[3], b2[3], nr[3];
#pragma unroll
        for (int d = 0; d < 3; ++d) { b1[d] = bb[0][d] - bb[1][d]; b2[d] = bb[2][d] - bb[1][d]; }
        nr[0] = b1[1] * b2[2] - b1[2] * b2[1];
        nr[1] = b1[2] * b2[0] - b1[0] * b2[2];
        nr[2] = b1[0] * b2[1] - b1[1] * b2[0];
#pragma unroll
        for (int a = 0; a < 4; ++a)
#pragma unroll
            for (int d = 0; d < 3; ++d) Xall[t * 15 + a * 3 + d] = bb[a][d];
#pragma unroll
        for (int d = 0; d < 3; ++d) {
            float xv = 0.58273431f * nr[d] + (-0.56802827f) * b1[d] + (-0.54067466f) * b2[d] + bb[1][d];
            Xall[t * 15 + 12 + d] = xv;
        }
        CA4[t] = make_float4(bb[1][0], bb[1][1], bb[1][2], mask[t]);
    } else {
        // pack W_e (416x128) into MFMA B-fragment order, bf16
        int t = (bid - 16) * 256 + threadIdx.x;
        if (t >= 13 * 8 * 64 * 8) return;
        int j = t & 7;
        int lane = (t >> 3) & 63;
        int nt = (t >> 9) & 7;
        int kt = t >> 12;
        int k = kt * 32 + (lane >> 4) * 8 + j;
        int n = nt * 16 + (lane & 15);
        Wp[t] = (short)bf16_rn(We[k * 128 + n]);
    }
}

// RBF row of 16 values via 2-anchor ratio recurrence: 6 exp2 instead of 16.
__device__ __forceinline__ void rbf16(float D, unsigned short* dst) {
    const float s1   = 0.96089793f;    // 0.8*sqrt(log2 e)
    const float dlt2 = 1.64146638f;    // dlt^2
    const float tdl  = 2.56239448f;    // 2*dlt
    const float Cg   = 0.10273972f;    // exp2(-2*dlt^2)
    float u0 = __builtin_fmaf(D, s1, -1.92179585f);   // c00 = 2*s1
    uint4 qa, qb;
    {
        float ua = u0 - 5.12478895f;                  // anchor i=4
        float va = __builtin_amdgcn_exp2f(-(ua * ua));
        float eu = fminf(__builtin_fmaf(tdl, ua, -dlt2), 120.0f);   // clamp: avoid 0*inf=NaN
        float ed = fminf(__builtin_fmaf(-tdl, ua, -dlt2), 120.0f);
        float gu = __builtin_amdgcn_exp2f(eu);
        float gd = __builtin_amdgcn_exp2f(ed);
        float v4 = va;
        float v5 = v4 * gu; float g2 = gu * Cg;
        float v6 = v5 * g2;
        float v7 = v6 * (g2 * Cg);
        float v3 = v4 * gd; float h2 = gd * Cg;
        float v2 = v3 * h2; float h3 = h2 * Cg;
        float v1 = v2 * h3;
        float v0 = v1 * (h3 * Cg);
        qa.x = pkbf2(v0, v1); qa.y = pkbf2(v2, v3);
        qa.z = pkbf2(v4, v5); qa.w = pkbf2(v6, v7);
    }
    {
        float ub = u0 - 15.37436684f;                 // anchor i=12
        float vb = __builtin_amdgcn_exp2f(-(ub * ub));
        float eu = fminf(__builtin_fmaf(tdl, ub, -dlt2), 120.0f);
        float ed = fminf(__builtin_fmaf(-tdl, ub, -dlt2), 120.0f);
        float gu = __builtin_amdgcn_exp2f(eu);
        float gd = __builtin_amdgcn_exp2f(ed);
        float v12 = vb;
        float v13 = v12 * gu; float g2 = gu * Cg;
        float v14 = v13 * g2;
        float v15 = v14 * (g2 * Cg);
        float v11 = v12 * gd; float h2 = gd * Cg;
        float v10 = v11 * h2; float h3 = h2 * Cg;
        float v9  = v10 * h3;
        float v8  = v9 * (h3 * Cg);
        qb.x = pkbf2(v8, v9);   qb.y = pkbf2(v10, v11);
        qb.z = pkbf2(v12, v13); qb.w = pkbf2(v14, v15);
    }
    *(uint4*)dst = qa;
    *(uint4*)(dst + 8) = qb;
}

// ---------------- Fused kernel: exact 48-NN topk -> features -> MFMA GEMM^T -> LN ----
// LDS union (19456 B -> 19968 w/ granule -> 8 blocks/CU):
//  topk phase:  [0..16384) hist 4096 bins u32 | [16384..17408) buf[128] u64
//  edge phase:  [0..16128) Asm bf16[48*168] | [16128..16192) Xq | [16192..19072) Xn
//               [19072..19264) eidxl
//  LN phase:    partials overlays Xn [16192..17728) ; stats float2[48] overlays eidxl
__global__ __launch_bounds__(256, 8) void edge_kernel(
    const float4* __restrict__ CA4, const float* __restrict__ Xall,
    const int* __restrict__ ridx, const float* __restrict__ Wpos,
    const float* __restrict__ bpos, const short* __restrict__ Wp,
    const float* __restrict__ lng, const float* __restrict__ lnb,
    float* __restrict__ out, float* __restrict__ out_idx) {
    __shared__ __align__(16) char smem[19456];
    unsigned int* histR = (unsigned int*)smem;                       // 4096 u32
    unsigned int* hist8 = (unsigned int*)smem;                       // 256 u32 (fallback)
    unsigned long long* buf = (unsigned long long*)(smem + 16384);   // 128 u64
    unsigned short* Asm = (unsigned short*)smem;
    float* Xq = (float*)(smem + 16128);
    float* Xn = (float*)(smem + 16192);
    int* eidxl = (int*)(smem + 19072);
    float2* stats = (float2*)(smem + 19072);                         // overlays eidxl (dead by LN)
    float* partials = (float*)(smem + 16192);                        // overlays Xn (dead by LN)
    __shared__ unsigned int nacc, wtot[4];
    __shared__ int sh_bin, sh_excl, sh_cnt;

    int bl = blockIdx.x;
    int base = (bl >> 11) << 11;
    int tid = threadIdx.x;
    int w = tid >> 6, lane = tid & 63;

    // ======================= phase T: exact top-48 =======================
    float4 q = CA4[bl];
    unsigned long long key[8];
#pragma unroll
    for (int i = 0; i < 8; ++i) {
        int j = tid + (i << 8);
        float4 c = CA4[base + j];
        float dx = __fsub_rn(q.x, c.x);
        float dy = __fsub_rn(q.y, c.y);
        float dz = __fsub_rn(q.z, c.z);
        // match numpy: ((dx*dx + dy*dy) + dz*dz) + 1e-6, no FMA contraction
        float s = __fadd_rn(__fadd_rn(__fmul_rn(dx, dx), __fmul_rn(dy, dy)), __fmul_rn(dz, dz));
        float D = __fsqrt_rn(__fadd_rn(s, 1e-6f));
        float m2 = __fmul_rn(q.w, c.w);
        float Dadj = __fadd_rn(__fmul_rn(D, m2), __fmul_rn(__fsub_rn(1.0f, m2), 1000000.0f));
        key[i] = (((unsigned long long)__float_as_uint(Dadj)) << 16) | (unsigned int)j;
    }

    // pass 1: 12-bit bins from key bits 46:35 (sign bit 47 is always 0) =
    // exp(8) + 4 mantissa bits -> 16 sub-bins/octave, fallback essentially never
    {
        uint4 z = make_uint4(0u, 0u, 0u, 0u);
#pragma unroll
        for (int i = 0; i < 4; ++i) ((uint4*)histR)[tid + (i << 8)] = z;
    }
    __syncthreads();
#pragma unroll
    for (int i = 0; i < 8; ++i)
        atomicAdd(&histR[(unsigned int)((key[i] >> 35) & 4095ull)], 1u);
    __syncthreads();

    // segmented scan over 4096 bins: 16 contiguous bins per thread
    unsigned int loc[16], lsum = 0;
#pragma unroll
    for (int j = 0; j < 4; ++j) {
        uint4 r4 = ((const uint4*)histR)[tid * 4 + j];
        loc[4 * j + 0] = r4.x; loc[4 * j + 1] = r4.y;
        loc[4 * j + 2] = r4.z; loc[4 * j + 3] = r4.w;
        lsum += (r4.x + r4.y) + (r4.z + r4.w);
    }
    unsigned int incl = lsum;
#pragma unroll
    for (int o = 1; o < 64; o <<= 1) {
        unsigned int v = __shfl_up(incl, o);
        if (lane >= o) incl += v;
    }
    if (lane == 63) wtot[w] = incl;
    __syncthreads();
    unsigned int cum = incl - lsum;
#pragma unroll
    for (int u = 0; u < 4; ++u) cum += (u < w) ? wtot[u] : 0u;
#pragma unroll
    for (int j = 0; j < 16; ++j) {
        if ((int)cum < 48 && 48 <= (int)(cum + loc[j])) {   // exactly one (tid,j)
            sh_bin = tid * 16 + j;
            sh_excl = (int)cum;
            sh_cnt = (int)loc[j];
        }
        cum += loc[j];
    }
    if (tid == 0) nacc = 0;   // covered by the barrier below
    __syncthreads();

    unsigned long long prefix = (unsigned long long)(unsigned int)sh_bin;
    int need = 48 - sh_excl;
    int cnt = sh_cnt;
    int shift = 35;

    // rare fallback: 8-bit refinement rounds
    while (cnt > 80 && shift > 0) {
        shift = (shift >= 8) ? (shift - 8) : 0;
        hist8[tid] = 0;
        __syncthreads();
#pragma unroll
        for (int i = 0; i < 8; ++i)
            if ((key[i] >> (shift + 8)) == prefix)
                atomicAdd(&hist8[(unsigned int)((key[i] >> shift) & 255ull)], 1u);
        __syncthreads();
        if (tid < 64) {
            unsigned int h0 = hist8[4 * tid + 0], h1 = hist8[4 * tid + 1];
            unsigned int h2 = hist8[4 * tid + 2], h3 = hist8[4 * tid + 3];
            unsigned int s4 = h0 + h1 + h2 + h3;
            unsigned int incl2 = s4;
#pragma unroll
            for (int o = 1; o < 64; o <<= 1) {
                unsigned int v = __shfl_up(incl2, o);
                if (tid >= o) incl2 += v;
            }
            unsigned int excl2 = incl2 - s4;
            if ((int)excl2 < need && need <= (int)incl2) {   // exactly one lane
                unsigned int cb = excl2;
                unsigned int hh[4] = {h0, h1, h2, h3};
                int bsel = 3;
#pragma unroll
                for (int bb2 = 0; bb2 < 4; ++bb2) {
                    if ((int)(cb + hh[bb2]) >= need) { bsel = bb2; break; }
                    cb += hh[bb2];
                }
                sh_bin = 4 * tid + bsel;
                sh_excl = (int)cb;
                sh_cnt = (int)hh[bsel];
            }
        }
        __syncthreads();
        prefix = (prefix << 8) | (unsigned long long)(unsigned int)sh_bin;
        need -= sh_excl;
        cnt = sh_cnt;
    }

    // collect: wave-aggregated push of definite + candidate keys (<=128)
#pragma unroll
    for (int i = 0; i < 8; ++i) {
        bool p = (key[i] >> shift) <= prefix;
        unsigned long long m = __ballot(p);
        if (m != 0ull) {
            int leader = __ffsll((long long)m) - 1;
            unsigned int bp2 = 0;
            if (lane == leader) bp2 = atomicAdd(&nacc, (unsigned int)__popcll(m));
            bp2 = (unsigned int)__shfl((int)bp2, leader);
            if (p) {
                unsigned int pos = bp2 + (unsigned int)__popcll(m & ((1ull << lane) - 1ull));
                if (pos < 128) buf[pos] = key[i];
            }
        }
    }
    __syncthreads();
    int mcnt = (int)nacc;
    if (mcnt > 128) mcnt = 128;

    // rank: 2 threads per entry, each counts half of [0,mcnt), combine via shfl
    if (tid < 2 * mcnt) {
        int e = tid >> 1, h = tid & 1;
        unsigned long long k = buf[e];
        int lo = h ? (mcnt >> 1) : 0;
        int hi = h ? mcnt : (mcnt >> 1);
        int rank = 0;
        for (int u = lo; u < hi; ++u) rank += (buf[u] < k) ? 1 : 0;
        rank += __shfl_xor(rank, 1);     // partner tid^1 = other half of same entry
        if (h == 0 && rank < KNB) {
            int j = (int)(k & 0xffffull);
            eidxl[rank] = j;
            out_idx[bl * KNB + rank] = (float)j;   // plain store: tiny, L2-merged
        }
    }
    __syncthreads();

    // ======================= phase E: edge features =======================
    int myoff = 0;                      // rel-pos offset lives in a register:
    if (tid < KNB) {                    // producer thread == consumer thread
        int j = eidxl[tid];
        myoff = min(max(ridx[bl] - ridx[base + j] + 32, 0), 64);
    }
    if (tid < 15) Xq[tid] = Xall[bl * 15 + tid];
    for (int f = tid; f < KNB * 15; f += 256) {
        int k = f / 15, d = f - k * 15;
        int j = eidxl[k];
        Xn[f] = Xall[(base + j) * 15 + d];
    }
    __syncthreads();

    int quad = lane >> 4, lr = lane & 15;
    // acc[et][wt]: E^T tile -- edge tile et (N dim), EOUT tile 2w+wt (M dim).
    // lane holds: edge = et*16 + (lane&15), EOUT cols = (2w+wt)*16 + quad*4 + r
    f32x4 acc[3][2];
#pragma unroll
    for (int et = 0; et < 3; ++et)
#pragma unroll
        for (int wt = 0; wt < 2; ++wt) acc[et][wt] = (f32x4){0.f, 0.f, 0.f, 0.f};

    auto gemm_chunk = [&](int ktBase, int ktCnt) {
#pragma unroll
        for (int ktl = 0; ktl < ktCnt; ++ktl) {
            int kt = ktBase + ktl;
            short8 bf0 = *(const short8*)(Wp + (((kt * 8 + 2 * w + 0) * 64 + lane) << 3));
            short8 bf1 = *(const short8*)(Wp + (((kt * 8 + 2 * w + 1) * 64 + lane) << 3));
#pragma unroll
            for (int et = 0; et < 3; ++et) {
                short8 af = *(const short8*)(&Asm[(et * 16 + lr) * CSTRIDE + ktl * 32 + quad * 8]);
                // swapped operands: D = W^T x A^T = E^T  (A/B frag layouts are symmetric)
                acc[et][0] = __builtin_amdgcn_mfma_f32_16x16x32_bf16(bf0, af, acc[et][0], 0, 0, 0);
                acc[et][1] = __builtin_amdgcn_mfma_f32_16x16x32_bf16(bf1, af, acc[et][1], 0, 0, 0);
            }
        }
    };

    // RBF fill with inline distance. k-major: lanes sweep atom-pairs within a row,
    // so the two ds_write_b128 per call land in contiguous 256B row segments
    // (bank-spread) and Xq/Xn reads broadcast across the 8-lane group.
    auto fill_rbf = [&](int prBase, int prCount, int colBase) {
        int total = prCount * KNB;
        for (int it = tid; it < total; it += 256) {
            int k = it / prCount, prl = it - k * prCount;
            int pr = prBase + prl;
            int a = pr / 5, c = pr - a * 5;
            float dx = Xq[a * 3 + 0] - Xn[k * 15 + c * 3 + 0];
            float dy = Xq[a * 3 + 1] - Xn[k * 15 + c * 3 + 1];
            float dz = Xq[a * 3 + 2] - Xn[k * 15 + c * 3 + 2];
            float D = __builtin_amdgcn_sqrtf(dx * dx + dy * dy + dz * dz + 1e-6f);
            rbf16(D, Asm + k * CSTRIDE + colBase + prl * 16);
        }
    };

    // ---- chunk 0: kt 0..4, cols 0..159 (16 pos cols + atom-pairs 0..8) ----
    if (tid < KNB) {
        const float4* wr = (const float4*)(Wpos + myoff * 16);
        const float4* bp = (const float4*)bpos;
        float4 a0 = wr[0], a1 = wr[1], a2 = wr[2], a3 = wr[3];
        float4 b0 = bp[0], b1 = bp[1], b2 = bp[2], b3 = bp[3];
        uint4 o1, o2;
        o1.x = pkbf2(a0.x + b0.x, a0.y + b0.y); o1.y = pkbf2(a0.z + b0.z, a0.w + b0.w);
        o1.z = pkbf2(a1.x + b1.x, a1.y + b1.y); o1.w = pkbf2(a1.z + b1.z, a1.w + b1.w);
        o2.x = pkbf2(a2.x + b2.x, a2.y + b2.y); o2.y = pkbf2(a2.z + b2.z, a2.w + b2.w);
        o2.z = pkbf2(a3.x + b3.x, a3.y + b3.y); o2.w = pkbf2(a3.z + b3.z, a3.w + b3.w);
        unsigned short* dst = Asm + tid * CSTRIDE;
        *(uint4*)dst = o1;
        *(uint4*)(dst + 8) = o2;
    }
    fill_rbf(0, 9, 16);
    __syncthreads();
    gemm_chunk(0, 5);
    __syncthreads();

    // ---- chunk 1: kt 5..8, cols 160..287 (atom-pairs 9..16) ----
    fill_rbf(9, 8, 0);
    __syncthreads();
    gemm_chunk(5, 4);
    __syncthreads();

    // ---- chunk 2: kt 9..12, cols 288..415 (atom-pairs 17..24) ----
    fill_rbf(17, 8, 0);
    __syncthreads();
    gemm_chunk(9, 4);
    // (no barrier needed: all Xn reads completed before the pre-gemm barrier;
    //  partials [16192,17728) is disjoint from Asm [0,16128) that gemm reads)

    // ======================= phase L: LayerNorm (E^T layout) =======================
    // lane owns 8 cols of edge (et*16+lr) per et: local sum + 2-step quad reduce
#pragma unroll
    for (int et = 0; et < 3; ++et) {
        float s = 0.f, qs = 0.f;
#pragma unroll
        for (int wt = 0; wt < 2; ++wt)
#pragma unroll
            for (int r = 0; r < 4; ++r) {
                float v = acc[et][wt][r];
                s += v;
                qs = __builtin_fmaf(v, v, qs);
            }
        s += __shfl_xor(s, 16); qs += __shfl_xor(qs, 16);
        s += __shfl_xor(s, 32); qs += __shfl_xor(qs, 32);
        if (quad == 0)
            *(float2*)(partials + (et * 16 + lr) * 8 + w * 2) = make_float2(s, qs);
    }
    __syncthreads();

    if (tid < KNB) {
        float4 p0 = *(const float4*)(partials + tid * 8);
        float4 p1 = *(const float4*)(partials + tid * 8 + 4);
        float s = (p0.x + p0.z) + (p1.x + p1.z);
        float qs = (p0.y + p0.w) + (p1.y + p1.w);
        float mean = s * 0.0078125f;
        float var = __builtin_fmaf(-mean, mean, qs * 0.0078125f);
        stats[tid] = make_float2(mean, rsqrtf(var + 1e-5f));
    }
    __syncthreads();

    // normalize + float4 nontemporal stores (keeps L2 for the read-set)
    f32x4 gv[2], bv[2];
#pragma unroll
    for (int wt = 0; wt < 2; ++wt) {
        int col = (2 * w + wt) * 16 + quad * 4;
        gv[wt] = *(const f32x4*)(lng + col);
        bv[wt] = *(const f32x4*)(lnb + col);
    }
#pragma unroll
    for (int et = 0; et < 3; ++et) {
        float2 st = stats[et * 16 + lr];
        float mean = st.x, inv = st.y;
        int erow = bl * KNB + et * 16 + lr;
#pragma unroll
        for (int wt = 0; wt < 2; ++wt) {
            int col = (2 * w + wt) * 16 + quad * 4;
            f32x4 o;
#pragma unroll
            for (int r = 0; r < 4; ++r)
                o[r] = __builtin_fmaf(acc[et][wt][r] - mean, inv * gv[wt][r], bv[wt][r]);
            __builtin_nontemporal_store(o, (f32x4*)(out + erow * EOUT + col));
        }
    }
}

extern "C" void kernel_launch(void* const* d_in, const int* in_sizes, int n_in,
                              void* d_out, int out_size, void* d_ws, size_t ws_size,
                              hipStream_t stream) {
    const float* X    = (const float*)d_in[0];
    // d_in[1] = X_m (unused by reference)
    const int*   S    = (const int*)d_in[2];
    const int*   ridx = (const int*)d_in[3];
    const float* mask = (const float*)d_in[4];
    const int*   tab  = (const int*)d_in[5];
    const float* Wpos = (const float*)d_in[6];
    const float* bpos = (const float*)d_in[7];
    const float* We   = (const float*)d_in[8];
    const float* lng  = (const float*)d_in[9];
    const float* lnb  = (const float*)d_in[10];
    float* out = (float*)d_out;

    char* ws = (char*)d_ws;
    float*  Xall = (float*)ws;                         // 4096*15*4   = 245760 B
    short*  Wp   = (short*)(ws + 245760);              // 53248*2     = 106496 B
    float4* CA4  = (float4*)(ws + 245760 + 106496);    // 4096*16     = 65536 B

    prep_kernel<<<224, 256, 0, stream>>>(X, S, tab, mask, We, Xall, CA4, Wp);
    edge_kernel<<<BLq, 256, 0, stream>>>(CA4, Xall, ridx, Wpos, bpos, Wp, lng, lnb,
                                         out, out + E_ELEMS);
}

// Round 10
// 165.756 us; speedup vs baseline: 1.0801x; 1.0096x over previous
//
#include <hip/hip_runtime.h>
#include <hip/hip_bf16.h>

// Problem constants (fixed by setup_inputs)
#define Bq 2
#define Lq 2048
#define BLq (Bq*Lq)          // 4096
#define KNB 48
#define NA 14
#define NTOK 21
#define NRBF 16
#define POSD 16
#define EOUT 128
#define CSTRIDE 168          // chunked A row stride (bf16 elems), 336B
#define E_ELEMS (BLq*KNB*EOUT)   // 25165824

typedef __attribute__((ext_vector_type(8))) short short8;
typedef __attribute__((ext_vector_type(4))) float f32x4;

__device__ __forceinline__ unsigned short bf16_rn(float x) {
    unsigned int u = __float_as_uint(x);
    unsigned int r = (u + 0x7fffu + ((u >> 16) & 1u)) >> 16;
    return (unsigned short)r;
}

__device__ __forceinline__ unsigned int pkbf2(float a, float b) {
    __hip_bfloat162 t = __float22bfloat162_rn(make_float2(a, b));
    union { __hip_bfloat162 h; unsigned int u; } cv; cv.h = t;
    return cv.u;
}

// ---------------- Kernel P: fused [xall (16 blocks)] + [W_e pack (208 blocks)] ----
// Xall rows padded to 16 floats (64B) for vectorized staging in edge_kernel.
__global__ void prep_kernel(const float* __restrict__ X, const int* __restrict__ S,
                            const int* __restrict__ table, const float* __restrict__ mask,
                            const float* __restrict__ We,
                            float* __restrict__ Xall, float4* __restrict__ CA4,
                            short* __restrict__ Wp) {
    int bid = blockIdx.x;
    if (bid < 16) {
        int t = bid * 256 + threadIdx.x;
        if (t >= BLq) return;
        int s = S[t];
        float bb[4][3];
#pragma unroll
        for (int a = 0; a < 4; ++a) {
            int ia = table[s * 4 + a];
#pragma unroll
            for (int d = 0; d < 3; ++d) bb[a][d] = X[(t * NA + ia) * 3 + d];
        }
        float b1[3], b2[3], nr[3];
#pragma unroll
        for (int d = 0; d < 3; ++d) { b1[d] = bb[0][d] - bb[1][d]; b2[d] = bb[2][d] - bb[1][d]; }
        nr[0] = b1[1] * b2[2] - b1[2] * b2[1];
        nr[1] = b1[2] * b2[0] - b1[0] * b2[2];
        nr[2] = b1[0] * b2[1] - b1[1] * b2[0];
#pragma unroll
        for (int a = 0; a < 4; ++a)
#pragma unroll
            for (int d = 0; d < 3; ++d) Xall[(t << 4) + a * 3 + d] = bb[a][d];
#pragma unroll
        for (int d = 0; d < 3; ++d) {
            float xv = 0.58273431f * nr[d] + (-0.56802827f) * b1[d] + (-0.54067466f) * b2[d] + bb[1][d];
            Xall[(t << 4) + 12 + d] = xv;
        }
        Xall[(t << 4) + 15] = 0.f;
        CA4[t] = make_float4(bb[1][0], bb[1][1], bb[1][2], mask[t]);
    } else {
        // pack W_e (416x128) into MFMA B-fragment order, bf16
        int t = (bid - 16) * 256 + threadIdx.x;
        if (t >= 13 * 8 * 64 * 8) return;
        int j = t & 7;
        int lane = (t >> 3) & 63;
        int nt = (t >> 9) & 7;
        int kt = t >> 12;
        int k = kt * 32 + (lane >> 4) * 8 + j;
        int n = nt * 16 + (lane & 15);
        Wp[t] = (short)bf16_rn(We[k * 128 + n]);
    }
}

// RBF row of 16 values via 2-anchor ratio recurrence: 6 exp2 instead of 16.
__device__ __forceinline__ void rbf16(float D, unsigned short* dst) {
    const float s1   = 0.96089793f;    // 0.8*sqrt(log2 e)
    const float dlt2 = 1.64146638f;    // dlt^2
    const float tdl  = 2.56239448f;    // 2*dlt
    const float Cg   = 0.10273972f;    // exp2(-2*dlt^2)
    float u0 = __builtin_fmaf(D, s1, -1.92179585f);   // c00 = 2*s1
    uint4 qa, qb;
    {
        float ua = u0 - 5.12478895f;                  // anchor i=4
        float va = __builtin_amdgcn_exp2f(-(ua * ua));
        float eu = fminf(__builtin_fmaf(tdl, ua, -dlt2), 120.0f);   // clamp: avoid 0*inf=NaN
        float ed = fminf(__builtin_fmaf(-tdl, ua, -dlt2), 120.0f);
        float gu = __builtin_amdgcn_exp2f(eu);
        float gd = __builtin_amdgcn_exp2f(ed);
        float v4 = va;
        float v5 = v4 * gu; float g2 = gu * Cg;
        float v6 = v5 * g2;
        float v7 = v6 * (g2 * Cg);
        float v3 = v4 * gd; float h2 = gd * Cg;
        float v2 = v3 * h2; float h3 = h2 * Cg;
        float v1 = v2 * h3;
        float v0 = v1 * (h3 * Cg);
        qa.x = pkbf2(v0, v1); qa.y = pkbf2(v2, v3);
        qa.z = pkbf2(v4, v5); qa.w = pkbf2(v6, v7);
    }
    {
        float ub = u0 - 15.37436684f;                 // anchor i=12
        float vb = __builtin_amdgcn_exp2f(-(ub * ub));
        float eu = fminf(__builtin_fmaf(tdl, ub, -dlt2), 120.0f);
        float ed = fminf(__builtin_fmaf(-tdl, ub, -dlt2), 120.0f);
        float gu = __builtin_amdgcn_exp2f(eu);
        float gd = __builtin_amdgcn_exp2f(ed);
        float v12 = vb;
        float v13 = v12 * gu; float g2 = gu * Cg;
        float v14 = v13 * g2;
        float v15 = v14 * (g2 * Cg);
        float v11 = v12 * gd; float h2 = gd * Cg;
        float v10 = v11 * h2; float h3 = h2 * Cg;
        float v9  = v10 * h3;
        float v8  = v9 * (h3 * Cg);
        qb.x = pkbf2(v8, v9);   qb.y = pkbf2(v10, v11);
        qb.z = pkbf2(v12, v13); qb.w = pkbf2(v14, v15);
    }
    *(uint4*)dst = qa;
    *(uint4*)(dst + 8) = qb;
}

// ---------------- Fused kernel: exact 48-NN topk -> features -> MFMA GEMM^T -> LN ----
// LDS union (19456 B -> 19968 w/ granule -> 8 blocks/CU):
//  topk phase:  [0..16384) hist 4096 bins u32 | [16384..17408) buf[128] u64
//  edge phase:  [0..16128) Asm bf16[48*168] | [16128..16192) Xq | [16192..19264) Xn[48*16]
//               [19264..19456) eidxl
//  LN phase:    partials overlays Xn [16192..17728) ; stats overlays Xn [17728..18112)
__global__ __launch_bounds__(256, 8) void edge_kernel(
    const float4* __restrict__ CA4, const float* __restrict__ Xall,
    const int* __restrict__ ridx, const float* __restrict__ Wpos,
    const float* __restrict__ bpos, const short* __restrict__ Wp,
    const float* __restrict__ lng, const float* __restrict__ lnb,
    float* __restrict__ out, float* __restrict__ out_idx) {
    __shared__ __align__(16) char smem[19456];
    unsigned int* histR = (unsigned int*)smem;                       // 4096 u32
    unsigned int* hist8 = (unsigned int*)smem;                       // 256 u32 (fallback)
    unsigned long long* buf = (unsigned long long*)(smem + 16384);   // 128 u64
    unsigned short* Asm = (unsigned short*)smem;
    float* Xq = (float*)(smem + 16128);
    float* Xn = (float*)(smem + 16192);                              // 48 x 16 floats
    int* eidxl = (int*)(smem + 19264);
    float* partials = (float*)(smem + 16192);                        // overlays Xn (dead by LN)
    float2* stats = (float2*)(smem + 17728);                         // overlays Xn tail
    __shared__ unsigned int nacc, wtot[4];
    __shared__ int sh_bin, sh_excl, sh_cnt;

    int bl = blockIdx.x;
    int base = (bl >> 11) << 11;
    int tid = threadIdx.x;
    int w = tid >> 6, lane = tid & 63;

    // ======================= phase T: exact top-48 =======================
    // clear histogram first: LDS stores drain under the CA4 load latency below
    {
        uint4 z = make_uint4(0u, 0u, 0u, 0u);
#pragma unroll
        for (int i = 0; i < 4; ++i) ((uint4*)histR)[tid + (i << 8)] = z;
    }

    float4 q = CA4[bl];
    unsigned int fb[8];                 // f32 bits of D_adj; index j = tid + (i<<8)
#pragma unroll
    for (int i = 0; i < 8; ++i) {
        int j = tid + (i << 8);
        float4 c = CA4[base + j];
        float dx = __fsub_rn(q.x, c.x);
        float dy = __fsub_rn(q.y, c.y);
        float dz = __fsub_rn(q.z, c.z);
        // match numpy: ((dx*dx + dy*dy) + dz*dz) + 1e-6, no FMA contraction
        float s = __fadd_rn(__fadd_rn(__fmul_rn(dx, dx), __fmul_rn(dy, dy)), __fmul_rn(dz, dz));
        float D = __fsqrt_rn(__fadd_rn(s, 1e-6f));
        float m2 = __fmul_rn(q.w, c.w);
        float Dadj = __fadd_rn(__fmul_rn(D, m2), __fmul_rn(__fsub_rn(1.0f, m2), 1000000.0f));
        fb[i] = __float_as_uint(Dadj);
    }
    __syncthreads();

    // pass 1: 12-bit bins from fb bits 30:19 (sign bit always 0) =
    // exp(8) + 4 mantissa bits -> 16 sub-bins/octave, fallback essentially never
#pragma unroll
    for (int i = 0; i < 8; ++i)
        atomicAdd(&histR[fb[i] >> 19], 1u);     // bit31=0 -> value < 4096
    __syncthreads();

    // segmented scan over 4096 bins: 16 contiguous bins per thread
    unsigned int loc[16], lsum = 0;
#pragma unroll
    for (int j = 0; j < 4; ++j) {
        uint4 r4 = ((const uint4*)histR)[tid * 4 + j];
        loc[4 * j + 0] = r4.x; loc[4 * j + 1] = r4.y;
        loc[4 * j + 2] = r4.z; loc[4 * j + 3] = r4.w;
        lsum += (r4.x + r4.y) + (r4.z + r4.w);
    }
    unsigned int incl = lsum;
#pragma unroll
    for (int o = 1; o < 64; o <<= 1) {
        unsigned int v = __shfl_up(incl, o);
        if (lane >= o) incl += v;
    }
    if (lane == 63) wtot[w] = incl;
    __syncthreads();
    unsigned int cum = incl - lsum;
#pragma unroll
    for (int u = 0; u < 4; ++u) cum += (u < w) ? wtot[u] : 0u;
#pragma unroll
    for (int j = 0; j < 16; ++j) {
        if ((int)cum < 48 && 48 <= (int)(cum + loc[j])) {   // exactly one (tid,j)
            sh_bin = tid * 16 + j;
            sh_excl = (int)cum;
            sh_cnt = (int)loc[j];
        }
        cum += loc[j];
    }
    if (tid == 0) nacc = 0;   // covered by the barrier below
    __syncthreads();

    unsigned int prefix = (unsigned int)sh_bin;
    int need = 48 - sh_excl;
    int cnt = sh_cnt;
    int shift = 19;           // shift within fb (== old u64 shift - 16)

    // rare fallback: 8-bit refinement rounds (32-bit predicates)
    while (cnt > 80 && shift > 0) {
        shift = (shift >= 8) ? (shift - 8) : 0;
        hist8[tid] = 0;
        __syncthreads();
#pragma unroll
        for (int i = 0; i < 8; ++i)
            if ((fb[i] >> (shift + 8)) == prefix)
                atomicAdd(&hist8[(fb[i] >> shift) & 255u], 1u);
        __syncthreads();
        if (tid < 64) {
            unsigned int h0 = hist8[4 * tid + 0], h1 = hist8[4 * tid + 1];
            unsigned int h2 = hist8[4 * tid + 2], h3 = hist8[4 * tid + 3];
            unsigned int s4 = h0 + h1 + h2 + h3;
            unsigned int incl2 = s4;
#pragma unroll
            for (int o = 1; o < 64; o <<= 1) {
                unsigned int v = __shfl_up(incl2, o);
                if (tid >= o) incl2 += v;
            }
            unsigned int excl2 = incl2 - s4;
            if ((int)excl2 < need && need <= (int)incl2) {   // exactly one lane
                unsigned int cb = excl2;
                unsigned int hh[4] = {h0, h1, h2, h3};
                int bsel = 3;
#pragma unroll
                for (int bb2 = 0; bb2 < 4; ++bb2) {
                    if ((int)(cb + hh[bb2]) >= need) { bsel = bb2; break; }
                    cb += hh[bb2];
                }
                sh_bin = 4 * tid + bsel;
                sh_excl = (int)cb;
                sh_cnt = (int)hh[bsel];
            }
        }
        __syncthreads();
        prefix = (prefix << 8) | (unsigned int)sh_bin;
        need -= sh_excl;
        cnt = sh_cnt;
    }

    // collect: wave-aggregated push of definite + candidate keys (<=128).
    // u64 key = (fb<<16)|j materialized only here; rank order == original.
#pragma unroll
    for (int i = 0; i < 8; ++i) {
        bool p = (fb[i] >> shift) <= prefix;
        unsigned long long m = __ballot(p);
        if (m != 0ull) {
            int leader = __ffsll((long long)m) - 1;
            unsigned int bp2 = 0;
            if (lane == leader) bp2 = atomicAdd(&nacc, (unsigned int)__popcll(m));
            bp2 = (unsigned int)__shfl((int)bp2, leader);
            if (p) {
                unsigned int pos = bp2 + (unsigned int)__popcll(m & ((1ull << lane) - 1ull));
                if (pos < 128)
                    buf[pos] = (((unsigned long long)fb[i]) << 16) | (unsigned int)(tid + (i << 8));
            }
        }
    }
    __syncthreads();
    int mcnt = (int)nacc;
    if (mcnt > 128) mcnt = 128;

    // rank: 2 threads per entry, each counts half of [0,mcnt), combine via shfl
    if (tid < 2 * mcnt) {
        int e = tid >> 1, h = tid & 1;
        unsigned long long k = buf[e];
        int lo = h ? (mcnt >> 1) : 0;
        int hi = h ? mcnt : (mcnt >> 1);
        int rank = 0;
        for (int u = lo; u < hi; ++u) rank += (buf[u] < k) ? 1 : 0;
        rank += __shfl_xor(rank, 1);     // partner tid^1 = other half of same entry
        if (h == 0 && rank < KNB) {
            int j = (int)(k & 0xffffull);
            eidxl[rank] = j;
            out_idx[bl * KNB + rank] = (float)j;   // plain store: tiny, L2-merged
        }
    }
    __syncthreads();

    // ======================= phase E: edge features =======================
    int myoff = 0;                      // rel-pos offset lives in a register:
    if (tid < KNB) {                    // producer thread == consumer thread
        int j = eidxl[tid];
        myoff = min(max(ridx[bl] - ridx[base + j] + 32, 0), 64);
    }
    if (tid < 16) Xq[tid] = Xall[(bl << 4) + tid];
    for (int v = tid; v < KNB * 4; v += 256) {       // 192 float4 loads, b128 LDS writes
        int k = v >> 2, part = v & 3;
        int j = eidxl[k];
        ((float4*)Xn)[v] = ((const float4*)(Xall + ((base + j) << 4)))[part];
    }
    __syncthreads();

    int quad = lane >> 4, lr = lane & 15;
    // acc[et][wt]: E^T tile -- edge tile et (N dim), EOUT tile 2w+wt (M dim).
    // lane holds: edge = et*16 + (lane&15), EOUT cols = (2w+wt)*16 + quad*4 + r
    f32x4 acc[3][2];
#pragma unroll
    for (int et = 0; et < 3; ++et)
#pragma unroll
        for (int wt = 0; wt < 2; ++wt) acc[et][wt] = (f32x4){0.f, 0.f, 0.f, 0.f};

    auto gemm_chunk = [&](int ktBase, int ktCnt) {
#pragma unroll
        for (int ktl = 0; ktl < ktCnt; ++ktl) {
            int kt = ktBase + ktl;
            short8 bf0 = *(const short8*)(Wp + (((kt * 8 + 2 * w + 0) * 64 + lane) << 3));
            short8 bf1 = *(const short8*)(Wp + (((kt * 8 + 2 * w + 1) * 64 + lane) << 3));
#pragma unroll
            for (int et = 0; et < 3; ++et) {
                short8 af = *(const short8*)(&Asm[(et * 16 + lr) * CSTRIDE + ktl * 32 + quad * 8]);
                // swapped operands: D = W^T x A^T = E^T  (A/B frag layouts are symmetric)
                acc[et][0] = __builtin_amdgcn_mfma_f32_16x16x32_bf16(bf0, af, acc[et][0], 0, 0, 0);
                acc[et][1] = __builtin_amdgcn_mfma_f32_16x16x32_bf16(bf1, af, acc[et][1], 0, 0, 0);
            }
        }
    };

    // RBF fill with inline distance. k-major: lanes sweep atom-pairs within a row.
    auto fill_rbf = [&](int prBase, int prCount, int colBase) {
        int total = prCount * KNB;
        for (int it = tid; it < total; it += 256) {
            int k = it / prCount, prl = it - k * prCount;
            int pr = prBase + prl;
            int a = pr / 5, c = pr - a * 5;
            float dx = Xq[a * 3 + 0] - Xn[(k << 4) + c * 3 + 0];
            float dy = Xq[a * 3 + 1] - Xn[(k << 4) + c * 3 + 1];
            float dz = Xq[a * 3 + 2] - Xn[(k << 4) + c * 3 + 2];
            float D = __builtin_amdgcn_sqrtf(dx * dx + dy * dy + dz * dz + 1e-6f);
            rbf16(D, Asm + k * CSTRIDE + colBase + prl * 16);
        }
    };

    // ---- chunk 0: kt 0..4, cols 0..159 (16 pos cols + atom-pairs 0..8) ----
    if (tid < KNB) {
        const float4* wr = (const float4*)(Wpos + myoff * 16);
        const float4* bp = (const float4*)bpos;
        float4 a0 = wr[0], a1 = wr[1], a2 = wr[2], a3 = wr[3];
        float4 b0 = bp[0], b1 = bp[1], b2 = bp[2], b3 = bp[3];
        uint4 o1, o2;
        o1.x = pkbf2(a0.x + b0.x, a0.y + b0.y); o1.y = pkbf2(a0.z + b0.z, a0.w + b0.w);
        o1.z = pkbf2(a1.x + b1.x, a1.y + b1.y); o1.w = pkbf2(a1.z + b1.z, a1.w + b1.w);
        o2.x = pkbf2(a2.x + b2.x, a2.y + b2.y); o2.y = pkbf2(a2.z + b2.z, a2.w + b2.w);
        o2.z = pkbf2(a3.x + b3.x, a3.y + b3.y); o2.w = pkbf2(a3.z + b3.z, a3.w + b3.w);
        unsigned short* dst = Asm + tid * CSTRIDE;
        *(uint4*)dst = o1;
        *(uint4*)(dst + 8) = o2;
    }
    fill_rbf(0, 9, 16);
    __syncthreads();
    gemm_chunk(0, 5);
    __syncthreads();

    // ---- chunk 1: kt 5..8, cols 160..287 (atom-pairs 9..16) ----
    fill_rbf(9, 8, 0);
    __syncthreads();
    gemm_chunk(5, 4);
    __syncthreads();

    // ---- chunk 2: kt 9..12, cols 288..415 (atom-pairs 17..24) ----
    fill_rbf(17, 8, 0);
    __syncthreads();
    gemm_chunk(9, 4);
    // (no barrier needed: all Xn reads completed before the pre-gemm barrier;
    //  partials/stats [16192,18112) are disjoint from Asm [0,16128) that gemm reads)

    // ======================= phase L: LayerNorm (E^T layout) =======================
    // lane owns 8 cols of edge (et*16+lr) per et: local sum + 2-step quad reduce
#pragma unroll
    for (int et = 0; et < 3; ++et) {
        float s = 0.f, qs = 0.f;
#pragma unroll
        for (int wt = 0; wt < 2; ++wt)
#pragma unroll
            for (int r = 0; r < 4; ++r) {
                float v = acc[et][wt][r];
                s += v;
                qs = __builtin_fmaf(v, v, qs);
            }
        s += __shfl_xor(s, 16); qs += __shfl_xor(qs, 16);
        s += __shfl_xor(s, 32); qs += __shfl_xor(qs, 32);
        if (quad == 0)
            *(float2*)(partials + (et * 16 + lr) * 8 + w * 2) = make_float2(s, qs);
    }
    __syncthreads();

    if (tid < KNB) {
        float4 p0 = *(const float4*)(partials + tid * 8);
        float4 p1 = *(const float4*)(partials + tid * 8 + 4);
        float s = (p0.x + p0.z) + (p1.x + p1.z);
        float qs = (p0.y + p0.w) + (p1.y + p1.w);
        float mean = s * 0.0078125f;
        float var = __builtin_fmaf(-mean, mean, qs * 0.0078125f);
        stats[tid] = make_float2(mean, rsqrtf(var + 1e-5f));
    }
    __syncthreads();

    // normalize + float4 nontemporal stores (keeps L2 for the read-set)
    f32x4 gv[2], bv[2];
#pragma unroll
    for (int wt = 0; wt < 2; ++wt) {
        int col = (2 * w + wt) * 16 + quad * 4;
        gv[wt] = *(const f32x4*)(lng + col);
        bv[wt] = *(const f32x4*)(lnb + col);
    }
#pragma unroll
    for (int et = 0; et < 3; ++et) {
        float2 st = stats[et * 16 + lr];
        float mean = st.x, inv = st.y;
        int erow = bl * KNB + et * 16 + lr;
#pragma unroll
        for (int wt = 0; wt < 2; ++wt) {
            int col = (2 * w + wt) * 16 + quad * 4;
            f32x4 o;
#pragma unroll
            for (int r = 0; r < 4; ++r)
                o[r] = __builtin_fmaf(acc[et][wt][r] - mean, inv * gv[wt][r], bv[wt][r]);
            __builtin_nontemporal_store(o, (f32x4*)(out + erow * EOUT + col));
        }
    }
}

extern "C" void kernel_launch(void* const* d_in, const int* in_sizes, int n_in,
                              void* d_out, int out_size, void* d_ws, size_t ws_size,
                              hipStream_t stream) {
    const float* X    = (const float*)d_in[0];
    // d_in[1] = X_m (unused by reference)
    const int*   S    = (const int*)d_in[2];
    const int*   ridx = (const int*)d_in[3];
    const float* mask = (const float*)d_in[4];
    const int*   tab  = (const int*)d_in[5];
    const float* Wpos = (const float*)d_in[6];
    const float* bpos = (const float*)d_in[7];
    const float* We   = (const float*)d_in[8];
    const float* lng  = (const float*)d_in[9];
    const float* lnb  = (const float*)d_in[10];
    float* out = (float*)d_out;

    char* ws = (char*)d_ws;
    float*  Xall = (float*)ws;                         // 4096*16*4   = 262144 B
    short*  Wp   = (short*)(ws + 262144);              // 53248*2     = 106496 B
    float4* CA4  = (float4*)(ws + 262144 + 106496);    // 4096*16     = 65536 B

    prep_kernel<<<224, 256, 0, stream>>>(X, S, tab, mask, We, Xall, CA4, Wp);
    edge_kernel<<<BLq, 256, 0, stream>>>(CA4, Xall, ridx, Wpos, bpos, Wp, lng, lnb,
                                         out, out + E_ELEMS);
}